// Round 1
// baseline (312.760 us; speedup 1.0000x reference)
//
#include <hip/hip_runtime.h>

// predict/target: fp32, shape (64, 3, 17, 4096)
// loss = sum((t-p)^2 * w[c]) / (bs*actionlen*seqlen),  w = {1, 1, 75825}
//
// Fused single-pass version:
//  - 4 B memset zeroes an arrival counter in d_ws (ws is re-poisoned by the
//    harness every iteration, so the counter MUST be reset per launch).
//  - One kernel: perfectly balanced grid (4352 blocks = exactly 17 blocks/CU
//    on 256 CUs), each thread 3 float4-pairs, fully unrolled, no bounds
//    checks. Per-block partial -> ws, device-scope atomic arrival, last
//    block reduces all partials in double and writes the scaled result.
//  - Generic 2-kernel fallback for any other size.

#define BLOCK_SIZE 256
#define ITERS 3
#define VEC_PER_CHAN 17408   // (17*4096)/4 : float4-groups per channel segment
#define W2 75825.0f          // MAXLEN
#define PARTIAL_OFF 64       // floats; counter lives at ws[0], partials at ws[64]

__device__ __forceinline__ float blockReduceF(float acc, float* smem) {
    #pragma unroll
    for (int off = 32; off > 0; off >>= 1)
        acc += __shfl_down(acc, off, 64);
    const int lane = threadIdx.x & 63;
    const int wid  = threadIdx.x >> 6;
    if (lane == 0) smem[wid] = acc;
    __syncthreads();
    float s = 0.0f;
    if (threadIdx.x == 0) {
        #pragma unroll
        for (int w = 0; w < BLOCK_SIZE / 64; ++w) s += smem[w];
    }
    return s;
}

// Exact fused kernel: grid covers n4 exactly (nblocks*BLOCK_SIZE*ITERS == n4).
__global__ __launch_bounds__(BLOCK_SIZE) void pm_mse_fused(
    const float4* __restrict__ p, const float4* __restrict__ t,
    float* __restrict__ ws, float* __restrict__ out,
    int stride /* total threads */, int nblocks, float scale) {
    const int tid = blockIdx.x * BLOCK_SIZE + threadIdx.x;

    float4 a[ITERS], b[ITERS];
    #pragma unroll
    for (int k = 0; k < ITERS; ++k) {
        const int i = tid + k * stride;
        a[k] = p[i];
        b[k] = t[i];
    }
    float acc = 0.0f;
    #pragma unroll
    for (int k = 0; k < ITERS; ++k) {
        const int i = tid + k * stride;
        float dx = b[k].x - a[k].x;
        float dy = b[k].y - a[k].y;
        float dz = b[k].z - a[k].z;
        float dw = b[k].w - a[k].w;
        float s = dx * dx + dy * dy + dz * dz + dw * dw;
        const int c = (i / VEC_PER_CHAN) % 3;   // vec4 never straddles a channel
        acc += (c == 2) ? s * W2 : s;
    }

    __shared__ float smem[BLOCK_SIZE / 64];
    float s = blockReduceF(acc, smem);

    unsigned int* counter = (unsigned int*)ws;
    float* partial = ws + PARTIAL_OFF;

    __shared__ bool amLast;
    if (threadIdx.x == 0) {
        partial[blockIdx.x] = s;
        __threadfence();                              // release partial (device scope)
        const unsigned int prev = atomicAdd(counter, 1u);
        amLast = (prev == (unsigned int)(nblocks - 1));
    }
    __syncthreads();
    if (!amLast) return;

    __threadfence();                                  // acquire all partials
    double dacc = 0.0;
    for (int i = threadIdx.x; i < nblocks; i += BLOCK_SIZE)
        dacc += (double)partial[i];
    #pragma unroll
    for (int off = 32; off > 0; off >>= 1)
        dacc += __shfl_down(dacc, off, 64);
    __shared__ double dsm[BLOCK_SIZE / 64];
    const int lane = threadIdx.x & 63;
    const int wid  = threadIdx.x >> 6;
    if (lane == 0) dsm[wid] = dacc;
    __syncthreads();
    if (threadIdx.x == 0) {
        double tot = 0.0;
        #pragma unroll
        for (int w = 0; w < BLOCK_SIZE / 64; ++w) tot += dsm[w];
        out[0] = (float)(tot * (double)scale);
    }
}

// ---- generic fallback (any n4) ----
__global__ __launch_bounds__(BLOCK_SIZE) void pm_mse_partial_generic(
    const float4* __restrict__ p, const float4* __restrict__ t,
    float* __restrict__ partial, int n4) {
    float acc = 0.0f;
    const int stride = gridDim.x * blockDim.x;
    for (int i = blockIdx.x * blockDim.x + threadIdx.x; i < n4; i += stride) {
        float4 a = p[i];
        float4 b = t[i];
        float dx = b.x - a.x;
        float dy = b.y - a.y;
        float dz = b.z - a.z;
        float dw = b.w - a.w;
        float s = dx * dx + dy * dy + dz * dz + dw * dw;
        int c = (i / VEC_PER_CHAN) % 3;
        acc += (c == 2) ? s * W2 : s;
    }
    __shared__ float smem[BLOCK_SIZE / 64];
    float s = blockReduceF(acc, smem);
    if (threadIdx.x == 0) partial[blockIdx.x] = s;
}

__global__ __launch_bounds__(BLOCK_SIZE) void pm_mse_final(
    const float* __restrict__ partial, int nblocks, float* __restrict__ out,
    float scale) {
    double acc = 0.0;
    for (int i = threadIdx.x; i < nblocks; i += blockDim.x)
        acc += (double)partial[i];
    for (int off = 32; off > 0; off >>= 1)
        acc += __shfl_down(acc, off, 64);
    __shared__ double smem[BLOCK_SIZE / 64];
    const int lane = threadIdx.x & 63;
    const int wid = threadIdx.x >> 6;
    if (lane == 0) smem[wid] = acc;
    __syncthreads();
    if (threadIdx.x == 0) {
        double s = 0.0;
        #pragma unroll
        for (int w = 0; w < BLOCK_SIZE / 64; ++w) s += smem[w];
        out[0] = (float)(s * (double)scale);
    }
}

extern "C" void kernel_launch(void* const* d_in, const int* in_sizes, int n_in,
                              void* d_out, int out_size, void* d_ws, size_t ws_size,
                              hipStream_t stream) {
    const float* predict = (const float*)d_in[0];
    const float* target  = (const float*)d_in[1];
    float* out = (float*)d_out;
    float* ws = (float*)d_ws;

    const int n = in_sizes[0];      // 64*3*17*4096 = 13,369,344 elements
    const int n4 = n / 4;           // 3,342,336 = 4352 * 256 * 3
    const float scale = 3.0f / (float)n;  // divisor = n / ddim

    const int chunk = BLOCK_SIZE * ITERS;   // 768
    if (n4 % chunk == 0 && (size_t)ws_size >= (PARTIAL_OFF + (size_t)(n4 / chunk)) * 4) {
        const int blocks = n4 / chunk;               // 4352 = 17 blocks/CU exactly
        const int stride = blocks * BLOCK_SIZE;      // 1,114,112
        hipMemsetAsync(d_ws, 0, sizeof(unsigned int), stream);  // zero arrival counter
        pm_mse_fused<<<blocks, BLOCK_SIZE, 0, stream>>>(
            (const float4*)predict, (const float4*)target, ws, out,
            stride, blocks, scale);
    } else {
        int blocks = (n4 + BLOCK_SIZE - 1) / BLOCK_SIZE;
        if (blocks > 2048) blocks = 2048;
        pm_mse_partial_generic<<<blocks, BLOCK_SIZE, 0, stream>>>(
            (const float4*)predict, (const float4*)target, ws + PARTIAL_OFF, n4);
        pm_mse_final<<<1, BLOCK_SIZE, 0, stream>>>(ws + PARTIAL_OFF, blocks, out, scale);
    }
}

// Round 2
// 155.517 us; speedup vs baseline: 2.0111x; 2.0111x over previous
//
#include <hip/hip_runtime.h>

// predict/target: fp32, shape (64, 3, 17, 4096)
// loss = sum((t-p)^2 * w[c]) / (bs*actionlen*seqlen),  w = {1, 1, 75825}
//
// Fused single-pass, FENCE-FREE cross-block handoff:
//  - Round-1 post-mortem: __threadfence() (buffer_wbl2 + waitcnt, a full L2
//    writeback) x4352 blocks serialized the fabric -> 227 us with 3% HBM BW
//    and 1.3% VALUBusy. The fence was flushing 4 MiB of L2 per XCD to
//    publish a single 4 B partial.
//  - Fix: publish partials with agent-scope atomic stores (sc-annotated
//    write-through to the coherent point, no L2 flush), order against the
//    arrival counter with s_waitcnt vmcnt(0) (acks THAT store only), and
//    read them back with agent-scope atomic loads. No wbl2 anywhere.
//  - Grid: 4352 blocks = exactly 17 blocks/CU on 256 CUs (balanced),
//    ITERS=3 float4-pairs per thread, fully unrolled, no bounds checks.
//  - Deterministic: partials land in a fixed array; last block sums them in
//    fixed order in double -> bitwise-stable result.

#define BLOCK_SIZE 256
#define ITERS 3
#define VEC_PER_CHAN 17408   // (17*4096)/4 : float4-groups per channel segment
#define W2 75825.0f          // MAXLEN
#define PARTIAL_OFF 64       // floats; counter at ws[0], partials at ws[64]

__device__ __forceinline__ float blockReduceF(float acc, float* smem) {
    #pragma unroll
    for (int off = 32; off > 0; off >>= 1)
        acc += __shfl_down(acc, off, 64);
    const int lane = threadIdx.x & 63;
    const int wid  = threadIdx.x >> 6;
    if (lane == 0) smem[wid] = acc;
    __syncthreads();
    float s = 0.0f;
    if (threadIdx.x == 0) {
        #pragma unroll
        for (int w = 0; w < BLOCK_SIZE / 64; ++w) s += smem[w];
    }
    return s;
}

// Exact fused kernel: grid covers n4 exactly (nblocks*BLOCK_SIZE*ITERS == n4).
__global__ __launch_bounds__(BLOCK_SIZE) void pm_mse_fused(
    const float4* __restrict__ p, const float4* __restrict__ t,
    float* __restrict__ ws, float* __restrict__ out,
    int stride /* total threads */, int nblocks, float scale) {
    const int tid = blockIdx.x * BLOCK_SIZE + threadIdx.x;

    float4 a[ITERS], b[ITERS];
    #pragma unroll
    for (int k = 0; k < ITERS; ++k) {
        const int i = tid + k * stride;
        a[k] = p[i];
        b[k] = t[i];
    }
    float acc = 0.0f;
    #pragma unroll
    for (int k = 0; k < ITERS; ++k) {
        const int i = tid + k * stride;
        float dx = b[k].x - a[k].x;
        float dy = b[k].y - a[k].y;
        float dz = b[k].z - a[k].z;
        float dw = b[k].w - a[k].w;
        float s = dx * dx + dy * dy + dz * dz + dw * dw;
        const int c = (i / VEC_PER_CHAN) % 3;   // vec4 never straddles a channel
        acc += (c == 2) ? s * W2 : s;
    }

    __shared__ float smem[BLOCK_SIZE / 64];
    float s = blockReduceF(acc, smem);

    unsigned int* counter = (unsigned int*)ws;
    float* partial = ws + PARTIAL_OFF;

    __shared__ bool amLast;
    if (threadIdx.x == 0) {
        // Agent-scope relaxed atomic store: write-through to the coherent
        // point (sc-annotated), NO buffer_wbl2.
        __hip_atomic_store(&partial[blockIdx.x], s,
                           __ATOMIC_RELAXED, __HIP_MEMORY_SCOPE_AGENT);
        // Order the partial store before the arrival increment: wait for the
        // store's ack only (cheap), not an L2 writeback.
        asm volatile("s_waitcnt vmcnt(0)" ::: "memory");
        const unsigned int prev = __hip_atomic_fetch_add(
            counter, 1u, __ATOMIC_RELAXED, __HIP_MEMORY_SCOPE_AGENT);
        amLast = (prev == (unsigned int)(nblocks - 1));
    }
    __syncthreads();
    if (!amLast) return;

    // All partials reached the coherent point before their counter bumps;
    // agent-scope loads fetch from the coherent point (no buffer_inv needed).
    double dacc = 0.0;
    for (int i = threadIdx.x; i < nblocks; i += BLOCK_SIZE)
        dacc += (double)__hip_atomic_load(&partial[i],
                    __ATOMIC_RELAXED, __HIP_MEMORY_SCOPE_AGENT);
    #pragma unroll
    for (int off = 32; off > 0; off >>= 1)
        dacc += __shfl_down(dacc, off, 64);
    __shared__ double dsm[BLOCK_SIZE / 64];
    const int lane = threadIdx.x & 63;
    const int wid  = threadIdx.x >> 6;
    if (lane == 0) dsm[wid] = dacc;
    __syncthreads();
    if (threadIdx.x == 0) {
        double tot = 0.0;
        #pragma unroll
        for (int w = 0; w < BLOCK_SIZE / 64; ++w) tot += dsm[w];
        out[0] = (float)(tot * (double)scale);
    }
}

// ---- generic fallback (any n4) ----
__global__ __launch_bounds__(BLOCK_SIZE) void pm_mse_partial_generic(
    const float4* __restrict__ p, const float4* __restrict__ t,
    float* __restrict__ partial, int n4) {
    float acc = 0.0f;
    const int stride = gridDim.x * blockDim.x;
    for (int i = blockIdx.x * blockDim.x + threadIdx.x; i < n4; i += stride) {
        float4 a = p[i];
        float4 b = t[i];
        float dx = b.x - a.x;
        float dy = b.y - a.y;
        float dz = b.z - a.z;
        float dw = b.w - a.w;
        float s = dx * dx + dy * dy + dz * dz + dw * dw;
        int c = (i / VEC_PER_CHAN) % 3;
        acc += (c == 2) ? s * W2 : s;
    }
    __shared__ float smem[BLOCK_SIZE / 64];
    float s = blockReduceF(acc, smem);
    if (threadIdx.x == 0) partial[blockIdx.x] = s;
}

__global__ __launch_bounds__(BLOCK_SIZE) void pm_mse_final(
    const float* __restrict__ partial, int nblocks, float* __restrict__ out,
    float scale) {
    double acc = 0.0;
    for (int i = threadIdx.x; i < nblocks; i += blockDim.x)
        acc += (double)partial[i];
    for (int off = 32; off > 0; off >>= 1)
        acc += __shfl_down(acc, off, 64);
    __shared__ double smem[BLOCK_SIZE / 64];
    const int lane = threadIdx.x & 63;
    const int wid = threadIdx.x >> 6;
    if (lane == 0) smem[wid] = acc;
    __syncthreads();
    if (threadIdx.x == 0) {
        double s = 0.0;
        #pragma unroll
        for (int w = 0; w < BLOCK_SIZE / 64; ++w) s += smem[w];
        out[0] = (float)(s * (double)scale);
    }
}

extern "C" void kernel_launch(void* const* d_in, const int* in_sizes, int n_in,
                              void* d_out, int out_size, void* d_ws, size_t ws_size,
                              hipStream_t stream) {
    const float* predict = (const float*)d_in[0];
    const float* target  = (const float*)d_in[1];
    float* out = (float*)d_out;
    float* ws = (float*)d_ws;

    const int n = in_sizes[0];      // 64*3*17*4096 = 13,369,344 elements
    const int n4 = n / 4;           // 3,342,336 = 4352 * 256 * 3
    const float scale = 3.0f / (float)n;  // divisor = n / ddim

    const int chunk = BLOCK_SIZE * ITERS;   // 768
    if (n4 % chunk == 0 && (size_t)ws_size >= (PARTIAL_OFF + (size_t)(n4 / chunk)) * 4) {
        const int blocks = n4 / chunk;               // 4352 = 17 blocks/CU exactly
        const int stride = blocks * BLOCK_SIZE;      // 1,114,112
        hipMemsetAsync(d_ws, 0, sizeof(unsigned int), stream);  // zero arrival counter
        pm_mse_fused<<<blocks, BLOCK_SIZE, 0, stream>>>(
            (const float4*)predict, (const float4*)target, ws, out,
            stride, blocks, scale);
    } else {
        int blocks = (n4 + BLOCK_SIZE - 1) / BLOCK_SIZE;
        if (blocks > 2048) blocks = 2048;
        pm_mse_partial_generic<<<blocks, BLOCK_SIZE, 0, stream>>>(
            (const float4*)predict, (const float4*)target, ws + PARTIAL_OFF, n4);
        pm_mse_final<<<1, BLOCK_SIZE, 0, stream>>>(ws + PARTIAL_OFF, blocks, out, scale);
    }
}

// Round 3
// 123.154 us; speedup vs baseline: 2.5396x; 1.2628x over previous
//
#include <hip/hip_runtime.h>

// predict/target: fp32, shape (64, 3, 17, 4096)
// loss = sum((t-p)^2 * w[c]) / (bs*actionlen*seqlen),  w = {1, 1, 75825}
//
// Two-kernel structure (round-2 post-mortem: ANY single-address cross-block
// sync -- threadfence (227us) or agent-scope arrival counter (63us) -- costs
// far more than a second graph-captured dispatch. Kernel boundary provides
// coherence for free.)
//
// Stage 1: 4352 blocks x 256 thr = exactly 17 blocks/CU (balanced), ITERS=3
//          float4-pairs per thread, fully unrolled, no bounds checks, ONE
//          integer division per thread (channel index rotates (seg0+k)%3
//          because stride/VEC_PER_CHAN = 64 == 1 mod 3). Plain partial store.
// Stage 2: single 256-thread block reduces 4352 partials (17/thread) in
//          double, fixed order -> deterministic; scales and writes out[0].

#define BLOCK_SIZE 256
#define ITERS 3
#define VEC_PER_CHAN 17408   // (17*4096)/4 : float4-groups per channel segment
#define W2 75825.0f          // MAXLEN

__device__ __forceinline__ float blockReduceF(float acc, float* smem) {
    #pragma unroll
    for (int off = 32; off > 0; off >>= 1)
        acc += __shfl_down(acc, off, 64);
    const int lane = threadIdx.x & 63;
    const int wid  = threadIdx.x >> 6;
    if (lane == 0) smem[wid] = acc;
    __syncthreads();
    float s = 0.0f;
    if (threadIdx.x == 0) {
        #pragma unroll
        for (int w = 0; w < BLOCK_SIZE / 64; ++w) s += smem[w];
    }
    return s;
}

// Exact kernel: grid covers n4 exactly (nblocks*BLOCK_SIZE*ITERS == n4),
// and stride == n4/3 is a whole number of channel segments (64 of them).
__global__ __launch_bounds__(BLOCK_SIZE) void pm_mse_partial_exact(
    const float4* __restrict__ p, const float4* __restrict__ t,
    float* __restrict__ partial, int stride /* total threads = n4/3 */) {
    const int tid = blockIdx.x * BLOCK_SIZE + threadIdx.x;

    // Channel index for k-step: (seg0 + k) % 3, one division per thread.
    // (stride / VEC_PER_CHAN == 64, and 64 % 3 == 1.)
    const int seg0 = tid / VEC_PER_CHAN;
    float w[ITERS];
    #pragma unroll
    for (int k = 0; k < ITERS; ++k)
        w[k] = (((seg0 + k) % 3) == 2) ? W2 : 1.0f;

    float4 a[ITERS], b[ITERS];
    #pragma unroll
    for (int k = 0; k < ITERS; ++k) {
        const int i = tid + k * stride;
        a[k] = p[i];
        b[k] = t[i];
    }
    float acc = 0.0f;
    #pragma unroll
    for (int k = 0; k < ITERS; ++k) {
        float dx = b[k].x - a[k].x;
        float dy = b[k].y - a[k].y;
        float dz = b[k].z - a[k].z;
        float dw = b[k].w - a[k].w;
        float s = dx * dx + dy * dy + dz * dz + dw * dw;
        acc += s * w[k];   // s*1.0f is bitwise s; order matches previous versions
    }

    __shared__ float smem[BLOCK_SIZE / 64];
    float s = blockReduceF(acc, smem);
    if (threadIdx.x == 0) partial[blockIdx.x] = s;
}

// ---- generic fallback (any n4) ----
__global__ __launch_bounds__(BLOCK_SIZE) void pm_mse_partial_generic(
    const float4* __restrict__ p, const float4* __restrict__ t,
    float* __restrict__ partial, int n4) {
    float acc = 0.0f;
    const int stride = gridDim.x * blockDim.x;
    for (int i = blockIdx.x * blockDim.x + threadIdx.x; i < n4; i += stride) {
        float4 a = p[i];
        float4 b = t[i];
        float dx = b.x - a.x;
        float dy = b.y - a.y;
        float dz = b.z - a.z;
        float dw = b.w - a.w;
        float s = dx * dx + dy * dy + dz * dz + dw * dw;
        int c = (i / VEC_PER_CHAN) % 3;
        acc += (c == 2) ? s * W2 : s;
    }
    __shared__ float smem[BLOCK_SIZE / 64];
    float s = blockReduceF(acc, smem);
    if (threadIdx.x == 0) partial[blockIdx.x] = s;
}

__global__ __launch_bounds__(BLOCK_SIZE) void pm_mse_final(
    const float* __restrict__ partial, int nblocks, float* __restrict__ out,
    float scale) {
    double acc = 0.0;
    for (int i = threadIdx.x; i < nblocks; i += blockDim.x)
        acc += (double)partial[i];
    #pragma unroll
    for (int off = 32; off > 0; off >>= 1)
        acc += __shfl_down(acc, off, 64);
    __shared__ double smem[BLOCK_SIZE / 64];
    const int lane = threadIdx.x & 63;
    const int wid = threadIdx.x >> 6;
    if (lane == 0) smem[wid] = acc;
    __syncthreads();
    if (threadIdx.x == 0) {
        double s = 0.0;
        #pragma unroll
        for (int w = 0; w < BLOCK_SIZE / 64; ++w) s += smem[w];
        out[0] = (float)(s * (double)scale);
    }
}

extern "C" void kernel_launch(void* const* d_in, const int* in_sizes, int n_in,
                              void* d_out, int out_size, void* d_ws, size_t ws_size,
                              hipStream_t stream) {
    const float* predict = (const float*)d_in[0];
    const float* target  = (const float*)d_in[1];
    float* out = (float*)d_out;
    float* partial = (float*)d_ws;

    const int n = in_sizes[0];      // 64*3*17*4096 = 13,369,344 elements
    const int n4 = n / 4;           // 3,342,336 = 4352 * 256 * 3
    const float scale = 3.0f / (float)n;  // divisor = n / ddim

    const int chunk = BLOCK_SIZE * ITERS;   // 768
    const int blocks_exact = n4 / chunk;    // 4352 = 17 blocks/CU exactly
    const bool exact_ok =
        (n4 % chunk == 0) &&
        ((n4 / ITERS) % VEC_PER_CHAN == 0) &&               // stride = whole segments
        (((n4 / ITERS) / VEC_PER_CHAN) % 3 == 1) &&          // 64 % 3 == 1 rotation
        ((size_t)ws_size >= (size_t)blocks_exact * 4);

    if (exact_ok) {
        const int stride = blocks_exact * BLOCK_SIZE;        // n4/3 = 1,114,112
        pm_mse_partial_exact<<<blocks_exact, BLOCK_SIZE, 0, stream>>>(
            (const float4*)predict, (const float4*)target, partial, stride);
        pm_mse_final<<<1, BLOCK_SIZE, 0, stream>>>(partial, blocks_exact, out, scale);
    } else {
        int blocks = (n4 + BLOCK_SIZE - 1) / BLOCK_SIZE;
        if (blocks > 2048) blocks = 2048;
        pm_mse_partial_generic<<<blocks, BLOCK_SIZE, 0, stream>>>(
            (const float4*)predict, (const float4*)target, partial, n4);
        pm_mse_final<<<1, BLOCK_SIZE, 0, stream>>>(partial, blocks, out, scale);
    }
}